// Round 1
// baseline (1899.722 us; speedup 1.0000x reference)
//
#include <hip/hip_runtime.h>
#include <stdint.h>

#define N_NODES 50000
#define N_EDGES 1600000
#define NCB 25      // col blocks of 2048 rows: 50000 -> 25 (2 MB source slice per block @512 feats)
#define CSHIFT 11

typedef __attribute__((ext_vector_type(8))) short bf16x8;
typedef __attribute__((ext_vector_type(4))) float f32x4;
typedef __attribute__((ext_vector_type(8))) unsigned short u16x8;

__device__ __forceinline__ float b2f(unsigned short u) {
  union { unsigned int i; float f; } v; v.i = ((unsigned int)u) << 16; return v.f;
}
__device__ __forceinline__ unsigned short f2b(float f) {
  union { float f; unsigned int i; } v; v.f = f;
  unsigned int u = v.i;
  u += 0x7fffu + ((u >> 16) & 1u);
  return (unsigned short)(u >> 16);
}

__device__ __forceinline__ void load_lds16(const void* g, void* l) {
  __builtin_amdgcn_global_load_lds(
      (const __attribute__((address_space(1))) unsigned int*)g,
      (__attribute__((address_space(3))) unsigned int*)l, 16, 0, 0);
}

__device__ __forceinline__ void fma8(float* acc, u16x8 u, float v) {
#pragma unroll
  for (int h = 0; h < 8; ++h) acc[h] = fmaf(v, b2f(u[h]), acc[h]);
}

// ---------------- row L2-normalize, fp32 -> bf16 ----------------
__global__ __launch_bounds__(256) void normalize_k(const float* __restrict__ x,
                                                   unsigned short* __restrict__ out) {
  int lane = threadIdx.x & 63;
  int row = blockIdx.x * 4 + (threadIdx.x >> 6);
  const float* p = x + (size_t)row * 512 + lane * 8;
  float4 a = ((const float4*)p)[0];
  float4 b = ((const float4*)p)[1];
  float ss = a.x*a.x + a.y*a.y + a.z*a.z + a.w*a.w
           + b.x*b.x + b.y*b.y + b.z*b.z + b.w*b.w;
#pragma unroll
  for (int off = 1; off < 64; off <<= 1) ss += __shfl_xor(ss, off, 64);
  float s = 1.0f / fmaxf(sqrtf(ss), 1e-12f);
  u16x8 o;
  o[0]=f2b(a.x*s); o[1]=f2b(a.y*s); o[2]=f2b(a.z*s); o[3]=f2b(a.w*s);
  o[4]=f2b(b.x*s); o[5]=f2b(b.y*s); o[6]=f2b(b.z*s); o[7]=f2b(b.w*s);
  *(u16x8*)(out + (size_t)row * 512 + lane * 8) = o;
}

// ---------------- CSR build, edges ordered by (row, col>>11) ----------------
__global__ __launch_bounds__(256) void hist2_k(const int* __restrict__ er, const int* __restrict__ ec,
                                               int* __restrict__ h2) {
  int i = blockIdx.x * 256 + threadIdx.x;
  if (i < N_EDGES) atomicAdd(&h2[er[i] * NCB + (ec[i] >> CSHIFT)], 1);
}

__global__ __launch_bounds__(256) void scan1_k(const int* __restrict__ deg, int* __restrict__ out,
                                               int* __restrict__ csum, int n) {
  __shared__ int sd[256];
  int t = threadIdx.x;
  int base = blockIdx.x * 1024;
  int v[4], s = 0;
#pragma unroll
  for (int j = 0; j < 4; ++j) {
    int idx = base + t * 4 + j;
    v[j] = (idx < n) ? deg[idx] : 0;
    s += v[j];
  }
  sd[t] = s;
  __syncthreads();
  for (int off = 1; off < 256; off <<= 1) {
    int xx = (t >= off) ? sd[t - off] : 0;
    __syncthreads();
    sd[t] += xx;
    __syncthreads();
  }
  if (t == 255) csum[blockIdx.x] = sd[255];
  int run = sd[t] - s;
#pragma unroll
  for (int j = 0; j < 4; ++j) {
    int idx = base + t * 4 + j;
    if (idx < n) out[idx] = run;
    run += v[j];
  }
}

// single-block parallel exclusive scan, n <= 1280
__global__ __launch_bounds__(256) void scan2p_k(int* __restrict__ csum, int n) {
  __shared__ int sd[256];
  int t = threadIdx.x;
  int v[5], s = 0;
#pragma unroll
  for (int j = 0; j < 5; ++j) {
    int idx = t * 5 + j;
    v[j] = (idx < n) ? csum[idx] : 0;
    s += v[j];
  }
  sd[t] = s;
  __syncthreads();
  for (int off = 1; off < 256; off <<= 1) {
    int xx = (t >= off) ? sd[t - off] : 0;
    __syncthreads();
    sd[t] += xx;
    __syncthreads();
  }
  int run = sd[t] - s;
#pragma unroll
  for (int j = 0; j < 5; ++j) {
    int idx = t * 5 + j;
    if (idx < n) csum[idx] = run;
    run += v[j];
  }
}

__global__ __launch_bounds__(256) void scan3_k(int* __restrict__ out, const int* __restrict__ csum, int n) {
  int i = blockIdx.x * 256 + threadIdx.x;
  if (i < n) out[i] += csum[i >> 10];
}

__global__ __launch_bounds__(256) void extract_k(const int* __restrict__ rs2, int* __restrict__ rs_s) {
  int i = blockIdx.x * 256 + threadIdx.x;
  if (i < N_NODES) rs_s[i] = rs2[i * NCB];
  if (i == N_NODES) rs_s[i] = N_EDGES;
}

__global__ __launch_bounds__(256) void scatter2_k(const int* __restrict__ er, const int* __restrict__ ec,
    const float* __restrict__ ev, int* __restrict__ head2, int2* __restrict__ ep) {
  int i = blockIdx.x * 256 + threadIdx.x;
  if (i < N_EDGES) {
    int r = er[i], c = ec[i];
    int p = atomicAdd(&head2[r * NCB + (c >> CSHIFT)], 1);
    ep[p] = make_int2(c, __float_as_int(ev[i]));
  }
}

// ---------------- W [K,N] fp32 -> WT [N,K] bf16 ----------------
__global__ __launch_bounds__(256) void wconv_k(const float* __restrict__ W,
                                               unsigned short* __restrict__ WT, int K, int N) {
  int i = blockIdx.x * 256 + threadIdx.x;
  if (i < N * K) {
    int n = i / K, k = i - n * K;
    WT[i] = f2b(W[(size_t)k * N + n]);
  }
}

// ---------------- CSR SpMM D=512: one wave per row ----------------
// Columns defensively clamped to [0, N_NODES) so an indexing bug reads in-bounds
// (absmax failure with counters) instead of faulting on poisoned workspace.
// MODE 0: raw bf16 out.  MODE 2: +bias, fp32 out (final layer).
template <int MODE>
__global__ __launch_bounds__(256) void spmm512_k(const unsigned short* __restrict__ in,
    const int* __restrict__ rs, const int2* __restrict__ ep,
    const float* __restrict__ bias, void* __restrict__ outv) {
  int lane = threadIdx.x & 63;
  int row = blockIdx.x * 4 + (threadIdx.x >> 6);
  int e0 = rs[row];
  int e1 = rs[row + 1];
  float acc[8] = {0.f, 0.f, 0.f, 0.f, 0.f, 0.f, 0.f, 0.f};
  const unsigned short* base = in + (size_t)lane * 8;
  int e = e0;
  if ((e & 1) && e < e1) {  // align to 16B so int4 ep loads are legal
    int2 p = ep[e];
    unsigned c = (unsigned)p.x < N_NODES ? (unsigned)p.x : 0u;
    u16x8 u = *(const u16x8*)(base + (size_t)c * 512);
    fma8(acc, u, __int_as_float(p.y));
    ++e;
  }
  for (; e + 4 <= e1; e += 4) {
    int4 q0 = *(const int4*)(&ep[e]);      // edges e, e+1
    int4 q1 = *(const int4*)(&ep[e + 2]);  // edges e+2, e+3
    unsigned c0 = (unsigned)q0.x < N_NODES ? (unsigned)q0.x : 0u;
    unsigned c1 = (unsigned)q0.z < N_NODES ? (unsigned)q0.z : 0u;
    unsigned c2 = (unsigned)q1.x < N_NODES ? (unsigned)q1.x : 0u;
    unsigned c3 = (unsigned)q1.z < N_NODES ? (unsigned)q1.z : 0u;
    u16x8 u0 = *(const u16x8*)(base + (size_t)c0 * 512);
    u16x8 u1 = *(const u16x8*)(base + (size_t)c1 * 512);
    u16x8 u2 = *(const u16x8*)(base + (size_t)c2 * 512);
    u16x8 u3 = *(const u16x8*)(base + (size_t)c3 * 512);
    fma8(acc, u0, __int_as_float(q0.y));
    fma8(acc, u1, __int_as_float(q0.w));
    fma8(acc, u2, __int_as_float(q1.y));
    fma8(acc, u3, __int_as_float(q1.w));
  }
  for (; e < e1; ++e) {
    int2 p = ep[e];
    unsigned c = (unsigned)p.x < N_NODES ? (unsigned)p.x : 0u;
    u16x8 u = *(const u16x8*)(base + (size_t)c * 512);
    fma8(acc, u, __int_as_float(p.y));
  }
  size_t obase = (size_t)row * 512 + lane * 8;
  if (MODE == 2) {
    float* out = (float*)outv;
    int bb = lane * 8;
    f32x4 o0, o1;
#pragma unroll
    for (int j = 0; j < 4; ++j) o0[j] = acc[j] + bias[bb + j];
#pragma unroll
    for (int j = 0; j < 4; ++j) o1[j] = acc[4 + j] + bias[bb + 4 + j];
    __builtin_nontemporal_store(o0, (f32x4*)(out + obase));
    __builtin_nontemporal_store(o1, (f32x4*)(out + obase + 4));
  } else {
    unsigned short* out = (unsigned short*)outv;
    u16x8 o;
#pragma unroll
    for (int h = 0; h < 8; ++h) o[h] = f2b(acc[h]);
    __builtin_nontemporal_store(o, (u16x8*)(out + obase));
  }
}

// ---------------- CSR SpMM D=1024, slices fused: one wave per row, 2KB/edge ----
// bias + leaky_relu(0.2), bf16 out (middle layer).
__global__ __launch_bounds__(256) void spmm1024_k(const unsigned short* __restrict__ in,
    const int* __restrict__ rs, const int2* __restrict__ ep,
    const float* __restrict__ bias, unsigned short* __restrict__ out) {
  int lane = threadIdx.x & 63;
  int row = blockIdx.x * 4 + (threadIdx.x >> 6);
  int e0 = rs[row];
  int e1 = rs[row + 1];
  float a0[8] = {0.f, 0.f, 0.f, 0.f, 0.f, 0.f, 0.f, 0.f};
  float a1[8] = {0.f, 0.f, 0.f, 0.f, 0.f, 0.f, 0.f, 0.f};
  const unsigned short* base = in + (size_t)lane * 8;
  int e = e0;
  if ((e & 1) && e < e1) {
    int2 p = ep[e];
    unsigned c = (unsigned)p.x < N_NODES ? (unsigned)p.x : 0u;
    const unsigned short* r = base + (size_t)c * 1024;
    u16x8 x0 = *(const u16x8*)r;
    u16x8 x1 = *(const u16x8*)(r + 512);
    float v = __int_as_float(p.y);
    fma8(a0, x0, v);
    fma8(a1, x1, v);
    ++e;
  }
  for (; e + 2 <= e1; e += 2) {
    int4 q = *(const int4*)(&ep[e]);  // edges e, e+1
    unsigned c0 = (unsigned)q.x < N_NODES ? (unsigned)q.x : 0u;
    unsigned c1 = (unsigned)q.z < N_NODES ? (unsigned)q.z : 0u;
    const unsigned short* r0 = base + (size_t)c0 * 1024;
    const unsigned short* r1 = base + (size_t)c1 * 1024;
    u16x8 x0 = *(const u16x8*)r0;
    u16x8 x1 = *(const u16x8*)(r0 + 512);
    u16x8 y0 = *(const u16x8*)r1;
    u16x8 y1 = *(const u16x8*)(r1 + 512);
    float v0 = __int_as_float(q.y), v1 = __int_as_float(q.w);
    fma8(a0, x0, v0);
    fma8(a1, x1, v0);
    fma8(a0, y0, v1);
    fma8(a1, y1, v1);
  }
  if (e < e1) {
    int2 p = ep[e];
    unsigned c = (unsigned)p.x < N_NODES ? (unsigned)p.x : 0u;
    const unsigned short* r = base + (size_t)c * 1024;
    u16x8 x0 = *(const u16x8*)r;
    u16x8 x1 = *(const u16x8*)(r + 512);
    float v = __int_as_float(p.y);
    fma8(a0, x0, v);
    fma8(a1, x1, v);
  }
  int bb = lane * 8;
  u16x8 o0, o1;
#pragma unroll
  for (int h = 0; h < 8; ++h) {
    float x = a0[h] + bias[bb + h];
    x = x >= 0.f ? x : 0.2f * x;
    o0[h] = f2b(x);
  }
#pragma unroll
  for (int h = 0; h < 8; ++h) {
    float x = a1[h] + bias[512 + bb + h];
    x = x >= 0.f ? x : 0.2f * x;
    o1[h] = f2b(x);
  }
  size_t ob = (size_t)row * 1024 + bb;
  __builtin_nontemporal_store(o0, (u16x8*)(out + ob));
  __builtin_nontemporal_store(o1, (u16x8*)(out + ob + 512));
}

// ---------------- bf16 MFMA GEMM: C[M,N] = A[M,K] * BT[N,K]^T ----------------
template <bool BIAS_RELU>
__global__ __launch_bounds__(256) void gemm_bt_k(
    const unsigned short* __restrict__ A, const unsigned short* __restrict__ BT,
    const float* __restrict__ bias, unsigned short* __restrict__ C,
    int M, int N, int K) {
  __shared__ __align__(16) unsigned short sA[128 * 32];
  __shared__ __align__(16) unsigned short sB[128 * 32];
  int tid = threadIdx.x;
  int lane = tid & 63;
  int wid = tid >> 6;
  int wm = (wid & 1) * 64;
  int wn = (wid >> 1) * 64;
  int mblk = blockIdx.y * 128;
  int nblk = blockIdx.x * 128;
  const unsigned short* Bb = BT + (size_t)nblk * K;
  int c0 = tid, c1 = tid + 256;
  int ar0 = c0 >> 2, ac0 = (c0 & 3) * 8;
  int ar1 = c1 >> 2, ac1 = (c1 & 3) * 8;
  int ra0 = mblk + ar0; if (ra0 > M - 1) ra0 = M - 1;
  int ra1 = mblk + ar1; if (ra1 > M - 1) ra1 = M - 1;
  f32x4 acc[4][4] = {};
  for (int k0 = 0; k0 < K; k0 += 32) {
    load_lds16(A + (size_t)ra0 * K + k0 + ac0, &sA[c0 * 8]);
    load_lds16(A + (size_t)ra1 * K + k0 + ac1, &sA[c1 * 8]);
    load_lds16(Bb + (size_t)ar0 * K + k0 + ac0, &sB[c0 * 8]);
    load_lds16(Bb + (size_t)ar1 * K + k0 + ac1, &sB[c1 * 8]);
    __syncthreads();
    bf16x8 af[4], bfr[4];
    int kq = (lane >> 4) * 8;
    int mr = wm + (lane & 15);
    int nr = wn + (lane & 15);
#pragma unroll
    for (int i = 0; i < 4; ++i) af[i] = *(const bf16x8*)&sA[(mr + i * 16) * 32 + kq];
#pragma unroll
    for (int j = 0; j < 4; ++j) bfr[j] = *(const bf16x8*)&sB[(nr + j * 16) * 32 + kq];
#pragma unroll
    for (int i = 0; i < 4; ++i)
#pragma unroll
      for (int j = 0; j < 4; ++j)
        acc[i][j] = __builtin_amdgcn_mfma_f32_16x16x32_bf16(af[i], bfr[j], acc[i][j], 0, 0, 0);
    __syncthreads();
  }
  int quad = lane >> 4;
  int lc = lane & 15;
#pragma unroll
  for (int i = 0; i < 4; ++i) {
#pragma unroll
    for (int r = 0; r < 4; ++r) {
      int gm = mblk + wm + i * 16 + quad * 4 + r;
      if (gm < M) {
#pragma unroll
        for (int j = 0; j < 4; ++j) {
          int gn = nblk + wn + j * 16 + lc;
          float v = acc[i][j][r];
          if (BIAS_RELU) { v += bias[gn]; v = v >= 0.f ? v : 0.2f * v; }
          C[(size_t)gm * N + gn] = f2b(v);
        }
      }
    }
  }
}

extern "C" void kernel_launch(void* const* d_in, const int* in_sizes, int n_in,
                              void* d_out, int out_size, void* d_ws, size_t ws_size,
                              hipStream_t stream) {
  (void)in_sizes; (void)n_in; (void)out_size;
  const float* x  = (const float*)d_in[0];
  const int* erow = (const int*)d_in[1];
  const int* ecol = (const int*)d_in[2];
  const float* ev = (const float*)d_in[3];
  const float* W0 = (const float*)d_in[4];
  const float* b0 = (const float*)d_in[5];
  const float* W1 = (const float*)d_in[6];
  const float* b1 = (const float*)d_in[7];
  const float* W2 = (const float*)d_in[8];
  const float* b2 = (const float*)d_in[9];

  // ---- persistent meta (after the activation pool) ----
  const size_t POOL_T1 = 256000000;   // h1 full (204.8M, norm_out overlaid) + spmm0_out
  const size_t POOL_T2 = 204800000;   // norm + spmm0 + h1 half-chunk
  const size_t POOL_T3 = 153600000;   // norm + spmm0 + h1 quarter-chunk
  const size_t META = 12800000 + 200064 + 7340032;
  int tier = (ws_size >= POOL_T1 + META) ? 1 : (ws_size >= POOL_T2 + META) ? 2 : 3;
  size_t pool_sz = (tier == 1) ? POOL_T1 : (tier == 2) ? POOL_T2 : POOL_T3;

  char* ws = (char*)d_ws;
  int2*  ep   = (int2*)(ws + pool_sz);
  int*   rs_s = (int*)(ws + pool_sz + 12800000);
  unsigned short* w0t = (unsigned short*)(ws + pool_sz + 12800000 + 200064);
  unsigned short* w1t = w0t + (size_t)2048 * 512;
  unsigned short* w2t = w1t + (size_t)1024 * 2048;
  // build-time transients live in the (then-dead) activation pool
  int* rs2   = (int*)(ws);                  // N_NODES*NCB*4 = 5,000,000 B
  int* csum  = (int*)(ws + 5000064);        // ~5 KB
  int* head2 = (int*)(ws + 5008384);        // 5,000,000 B
  unsigned short* u = (unsigned short*)d_out;  // [N,1024] bf16 scratch

  // ---- CSR build: edges ordered by (row, col>>11) for L2 sweep locality ----
  const int NBIN = N_NODES * NCB;           // 1,250,000
  hipMemsetAsync(rs2, 0, (size_t)NBIN * 4, stream);
  hist2_k<<<6250, 256, 0, stream>>>(erow, ecol, rs2);
  scan1_k<<<1221, 256, 0, stream>>>(rs2, rs2, csum, NBIN);   // 1221*1024 >= 1.25M
  scan2p_k<<<1, 256, 0, stream>>>(csum, 1221);               // <= 1280 capacity
  scan3_k<<<4883, 256, 0, stream>>>(rs2, csum, NBIN);        // 4883*256 >= 1.25M
  extract_k<<<196, 256, 0, stream>>>(rs2, rs_s);
  hipMemcpyAsync(head2, rs2, (size_t)NBIN * 4, hipMemcpyDeviceToDevice, stream);
  scatter2_k<<<6250, 256, 0, stream>>>(erow, ecol, ev, head2, ep);

  // ---- weights -> transposed bf16 ----
  wconv_k<<<4096, 256, 0, stream>>>(W0, w0t, 512, 2048);
  wconv_k<<<8192, 256, 0, stream>>>(W1, w1t, 2048, 1024);
  wconv_k<<<2048, 256, 0, stream>>>(W2, w2t, 1024, 512);

  if (tier == 1) {
    unsigned short* h1        = (unsigned short*)(ws);              // 204.8M
    unsigned short* norm_out  = (unsigned short*)(ws);              // overlays h1 (dead before h1 written)
    unsigned short* spmm0_out = (unsigned short*)(ws + 204800000);  // 51.2M
    unsigned short* h2        = (unsigned short*)(ws);              // overlays h1 (dead)
    unsigned short* vbuf      = (unsigned short*)(ws + 102400000);
    normalize_k<<<12500, 256, 0, stream>>>(x, norm_out);
    spmm512_k<0><<<12500, 256, 0, stream>>>(norm_out, rs_s, ep, nullptr, spmm0_out);
    gemm_bt_k<true ><<<dim3(16, 391), 256, 0, stream>>>(spmm0_out, w0t, b0, h1, N_NODES, 2048, 512);
    gemm_bt_k<false><<<dim3(8, 391), 256, 0, stream>>>(h1, w1t, nullptr, u, N_NODES, 1024, 2048);
    spmm1024_k<<<12500, 256, 0, stream>>>(u, rs_s, ep, b1, h2);
    gemm_bt_k<false><<<dim3(4, 391), 256, 0, stream>>>(h2, w2t, nullptr, vbuf, N_NODES, 512, 1024);
    spmm512_k<2><<<12500, 256, 0, stream>>>(vbuf, rs_s, ep, b2, (float*)d_out);
  } else {
    int nchunk = (tier == 2) ? 2 : 4;
    int crows = (tier == 2) ? 25000 : 12500;
    int ytiles = (tier == 2) ? 196 : 98;
    unsigned short* norm_out  = (unsigned short*)(ws);
    unsigned short* spmm0_out = (unsigned short*)(ws + 51200000);
    unsigned short* h1chunk   = (unsigned short*)(ws + 102400000);
    unsigned short* h2        = (unsigned short*)(ws);
    unsigned short* vbuf      = (unsigned short*)(ws + 102400000);
    normalize_k<<<12500, 256, 0, stream>>>(x, norm_out);
    spmm512_k<0><<<12500, 256, 0, stream>>>(norm_out, rs_s, ep, nullptr, spmm0_out);
    for (int c = 0; c < nchunk; ++c) {
      const unsigned short* a0 = spmm0_out + (size_t)c * crows * 512;
      unsigned short* uc = u + (size_t)c * crows * 1024;
      gemm_bt_k<true ><<<dim3(16, ytiles), 256, 0, stream>>>(a0, w0t, b0, h1chunk, crows, 2048, 512);
      gemm_bt_k<false><<<dim3(8, ytiles), 256, 0, stream>>>(h1chunk, w1t, nullptr, uc, crows, 1024, 2048);
    }
    spmm1024_k<<<12500, 256, 0, stream>>>(u, rs_s, ep, b1, h2);
    gemm_bt_k<false><<<dim3(4, 391), 256, 0, stream>>>(h2, w2t, nullptr, vbuf, N_NODES, 512, 1024);
    spmm512_k<2><<<12500, 256, 0, stream>>>(vbuf, rs_s, ep, b2, (float*)d_out);
  }
}

// Round 2
// 1813.246 us; speedup vs baseline: 1.0477x; 1.0477x over previous
//
#include <hip/hip_runtime.h>
#include <stdint.h>

#define N_NODES 50000
#define N_EDGES 1600000
#define NCB 13  // col blocks of 4096: 50000 -> 13

typedef __attribute__((ext_vector_type(8))) short bf16x8;
typedef __attribute__((ext_vector_type(4))) float f32x4;
typedef __attribute__((ext_vector_type(8))) unsigned short u16x8;

__device__ __forceinline__ float b2f(unsigned short u) {
  union { unsigned int i; float f; } v; v.i = ((unsigned int)u) << 16; return v.f;
}
__device__ __forceinline__ unsigned short f2b(float f) {
  union { float f; unsigned int i; } v; v.f = f;
  unsigned int u = v.i;
  u += 0x7fffu + ((u >> 16) & 1u);
  return (unsigned short)(u >> 16);
}

__device__ __forceinline__ void load_lds16(const void* g, void* l) {
  __builtin_amdgcn_global_load_lds(
      (const __attribute__((address_space(1))) unsigned int*)g,
      (__attribute__((address_space(3))) unsigned int*)l, 16, 0, 0);
}

// ---------------- row L2-normalize, fp32 -> bf16 ----------------
__global__ __launch_bounds__(256) void normalize_k(const float* __restrict__ x,
                                                   unsigned short* __restrict__ out) {
  int lane = threadIdx.x & 63;
  int row = blockIdx.x * 4 + (threadIdx.x >> 6);
  const float* p = x + (size_t)row * 512 + lane * 8;
  float4 a = ((const float4*)p)[0];
  float4 b = ((const float4*)p)[1];
  float ss = a.x*a.x + a.y*a.y + a.z*a.z + a.w*a.w
           + b.x*b.x + b.y*b.y + b.z*b.z + b.w*b.w;
#pragma unroll
  for (int off = 1; off < 64; off <<= 1) ss += __shfl_xor(ss, off, 64);
  float s = 1.0f / fmaxf(sqrtf(ss), 1e-12f);
  u16x8 o;
  o[0]=f2b(a.x*s); o[1]=f2b(a.y*s); o[2]=f2b(a.z*s); o[3]=f2b(a.w*s);
  o[4]=f2b(b.x*s); o[5]=f2b(b.y*s); o[6]=f2b(b.z*s); o[7]=f2b(b.w*s);
  *(u16x8*)(out + (size_t)row * 512 + lane * 8) = o;
}

// ---------------- CSR build, edges ordered by (row, col>>12) ----------------
__global__ __launch_bounds__(256) void hist2_k(const int* __restrict__ er, const int* __restrict__ ec,
                                               int* __restrict__ h2) {
  int i = blockIdx.x * 256 + threadIdx.x;
  if (i < N_EDGES) atomicAdd(&h2[er[i] * NCB + (ec[i] >> 12)], 1);
}

__global__ __launch_bounds__(256) void scan1_k(const int* __restrict__ deg, int* __restrict__ out,
                                               int* __restrict__ csum, int n) {
  __shared__ int sd[256];
  int t = threadIdx.x;
  int base = blockIdx.x * 1024;
  int v[4], s = 0;
#pragma unroll
  for (int j = 0; j < 4; ++j) {
    int idx = base + t * 4 + j;
    v[j] = (idx < n) ? deg[idx] : 0;
    s += v[j];
  }
  sd[t] = s;
  __syncthreads();
  for (int off = 1; off < 256; off <<= 1) {
    int xx = (t >= off) ? sd[t - off] : 0;
    __syncthreads();
    sd[t] += xx;
    __syncthreads();
  }
  if (t == 255) csum[blockIdx.x] = sd[255];
  int run = sd[t] - s;
#pragma unroll
  for (int j = 0; j < 4; ++j) {
    int idx = base + t * 4 + j;
    if (idx < n) out[idx] = run;
    run += v[j];
  }
}

// single-block parallel exclusive scan, n <= 768
__global__ __launch_bounds__(256) void scan2p_k(int* __restrict__ csum, int n) {
  __shared__ int sd[256];
  int t = threadIdx.x;
  int v[3], s = 0;
#pragma unroll
  for (int j = 0; j < 3; ++j) {
    int idx = t * 3 + j;
    v[j] = (idx < n) ? csum[idx] : 0;
    s += v[j];
  }
  sd[t] = s;
  __syncthreads();
  for (int off = 1; off < 256; off <<= 1) {
    int xx = (t >= off) ? sd[t - off] : 0;
    __syncthreads();
    sd[t] += xx;
    __syncthreads();
  }
  int run = sd[t] - s;
#pragma unroll
  for (int j = 0; j < 3; ++j) {
    int idx = t * 3 + j;
    if (idx < n) csum[idx] = run;
    run += v[j];
  }
}

__global__ __launch_bounds__(256) void scan3_k(int* __restrict__ out, const int* __restrict__ csum, int n) {
  int i = blockIdx.x * 256 + threadIdx.x;
  if (i < n) out[i] += csum[i >> 10];
}

__global__ __launch_bounds__(256) void extract_k(const int* __restrict__ rs2, int* __restrict__ rs_s) {
  int i = blockIdx.x * 256 + threadIdx.x;
  if (i < N_NODES) rs_s[i] = rs2[i * NCB];
  if (i == N_NODES) rs_s[i] = N_EDGES;
}

__global__ __launch_bounds__(256) void scatter2_k(const int* __restrict__ er, const int* __restrict__ ec,
    const float* __restrict__ ev, int* __restrict__ head2, int2* __restrict__ ep) {
  int i = blockIdx.x * 256 + threadIdx.x;
  if (i < N_EDGES) {
    int r = er[i], c = ec[i];
    int p = atomicAdd(&head2[r * NCB + (c >> 12)], 1);
    ep[p] = make_int2(c, __float_as_int(ev[i]));
  }
}

// ---------------- all three W [K,N] fp32 -> WT [N,K] bf16, one launch ----------------
__global__ __launch_bounds__(256) void wconv3_k(const float* __restrict__ W0f,
                                                const float* __restrict__ W1f,
                                                const float* __restrict__ W2f,
                                                unsigned short* __restrict__ w0t,
                                                unsigned short* __restrict__ w1t,
                                                unsigned short* __restrict__ w2t) {
  const int S0 = 512 * 2048;   // 1048576
  const int S1 = 2048 * 1024;  // 2097152
  const int S2 = 1024 * 512;   // 524288
  int i = blockIdx.x * 256 + threadIdx.x;
  if (i < S0) {
    int n = i / 512, k = i - n * 512;
    w0t[i] = f2b(W0f[(size_t)k * 2048 + n]);
  } else if (i < S0 + S1) {
    int j = i - S0;
    int n = j / 2048, k = j - n * 2048;
    w1t[j] = f2b(W1f[(size_t)k * 1024 + n]);
  } else if (i < S0 + S1 + S2) {
    int j = i - S0 - S1;
    int n = j / 1024, k = j - n * 1024;
    w2t[j] = f2b(W2f[(size_t)k * 512 + n]);
  }
}

// ---------------- CSR SpMM: one wave per (row, 512-feature slice) ----------------
// Columns defensively clamped to [0, N_NODES) so an indexing bug reads in-bounds
// (absmax failure with counters) instead of faulting on poisoned workspace.
template <int D, int MODE>
__global__ __launch_bounds__(256) void spmm_k(const unsigned short* __restrict__ in,
    const int* __restrict__ rs, const int2* __restrict__ ep,
    const float* __restrict__ bias, void* __restrict__ outv) {
  constexpr int NS = D / 512;
  int lane = threadIdx.x & 63;
  int blk = blockIdx.x;
  int slice = (NS == 1) ? 0 : (blk / 12500);
  int rowg = (NS == 1) ? blk : (blk - slice * 12500);
  int row = rowg * 4 + (threadIdx.x >> 6);
  int e0 = rs[row];
  int e1 = rs[row + 1];
  float acc[8] = {0.f, 0.f, 0.f, 0.f, 0.f, 0.f, 0.f, 0.f};
  const unsigned short* base = in + (size_t)slice * 512 + (size_t)lane * 8;
  int e = e0;
  for (; e + 4 <= e1; e += 4) {
    int2 p0 = ep[e];
    int2 p1 = ep[e + 1];
    int2 p2 = ep[e + 2];
    int2 p3 = ep[e + 3];
    unsigned c0 = (unsigned)p0.x < N_NODES ? (unsigned)p0.x : 0u;
    unsigned c1 = (unsigned)p1.x < N_NODES ? (unsigned)p1.x : 0u;
    unsigned c2 = (unsigned)p2.x < N_NODES ? (unsigned)p2.x : 0u;
    unsigned c3 = (unsigned)p3.x < N_NODES ? (unsigned)p3.x : 0u;
    u16x8 u0 = *(const u16x8*)(base + (size_t)c0 * D);
    u16x8 u1 = *(const u16x8*)(base + (size_t)c1 * D);
    u16x8 u2 = *(const u16x8*)(base + (size_t)c2 * D);
    u16x8 u3 = *(const u16x8*)(base + (size_t)c3 * D);
    float v0 = __int_as_float(p0.y), v1 = __int_as_float(p1.y);
    float v2 = __int_as_float(p2.y), v3 = __int_as_float(p3.y);
#pragma unroll
    for (int h = 0; h < 8; ++h) acc[h] = fmaf(v0, b2f(u0[h]), acc[h]);
#pragma unroll
    for (int h = 0; h < 8; ++h) acc[h] = fmaf(v1, b2f(u1[h]), acc[h]);
#pragma unroll
    for (int h = 0; h < 8; ++h) acc[h] = fmaf(v2, b2f(u2[h]), acc[h]);
#pragma unroll
    for (int h = 0; h < 8; ++h) acc[h] = fmaf(v3, b2f(u3[h]), acc[h]);
  }
  for (; e < e1; ++e) {
    int2 p = ep[e];
    unsigned c = (unsigned)p.x < N_NODES ? (unsigned)p.x : 0u;
    u16x8 u = *(const u16x8*)(base + (size_t)c * D);
    float v = __int_as_float(p.y);
#pragma unroll
    for (int h = 0; h < 8; ++h) acc[h] = fmaf(v, b2f(u[h]), acc[h]);
  }
  size_t obase = (size_t)row * D + (size_t)slice * 512 + lane * 8;
  int bbase = slice * 512 + lane * 8;
  if (MODE == 2) {
    float* out = (float*)outv;
#pragma unroll
    for (int j = 0; j < 8; ++j) out[obase + j] = acc[j] + bias[bbase + j];
  } else {
    unsigned short* out = (unsigned short*)outv;
    u16x8 o;
#pragma unroll
    for (int h = 0; h < 8; ++h) {
      float xo = acc[h];
      if (MODE == 1) {
        xo += bias[bbase + h];
        xo = xo >= 0.f ? xo : 0.2f * xo;
      }
      o[h] = f2b(xo);
    }
    *(u16x8*)(out + obase) = o;
  }
}

// ---------------- bf16 MFMA GEMM: C[M,N] = A[M,K] * BT[N,K]^T ----------------
// 1-D grid; bijective XCD chunking (each XCD owns a contiguous tile-row range)
// + 8-tile-row supertiles, x-fastest within: A fetched ~once per XCD instead of
// the pathological x==XCD aliasing of the natural dim3(gx,gy) mapping.
template <bool BIAS_RELU>
__global__ __launch_bounds__(256) void gemm_bt_k(
    const unsigned short* __restrict__ A, const unsigned short* __restrict__ BT,
    const float* __restrict__ bias, unsigned short* __restrict__ C,
    int M, int N, int K, int gx) {
  __shared__ __align__(16) unsigned short sA[128 * 32];
  __shared__ __align__(16) unsigned short sB[128 * 32];
  // ---- block swizzle (perf-only, bijective) ----
  int nwg = gridDim.x;
  int id = blockIdx.x;
  int q = nwg >> 3, r = nwg & 7;
  int xcd = id & 7, pos = id >> 3;
  int nid = (xcd < r ? xcd * (q + 1) : r * (q + 1) + (xcd - r) * q) + pos;
  const int G = 8;
  int gsz = gx * G;
  int grp = nid / gsz;
  int rem = nid - grp * gsz;
  int bx = rem % gx;
  int by = grp * G + rem / gx;

  int tid = threadIdx.x;
  int lane = tid & 63;
  int wid = tid >> 6;
  int wm = (wid & 1) * 64;
  int wn = (wid >> 1) * 64;
  int mblk = by * 128;
  int nblk = bx * 128;
  const unsigned short* Bb = BT + (size_t)nblk * K;
  int c0 = tid, c1 = tid + 256;
  int ar0 = c0 >> 2, ac0 = (c0 & 3) * 8;
  int ar1 = c1 >> 2, ac1 = (c1 & 3) * 8;
  int ra0 = mblk + ar0; if (ra0 > M - 1) ra0 = M - 1;
  int ra1 = mblk + ar1; if (ra1 > M - 1) ra1 = M - 1;
  f32x4 acc[4][4] = {};
  for (int k0 = 0; k0 < K; k0 += 32) {
    load_lds16(A + (size_t)ra0 * K + k0 + ac0, &sA[c0 * 8]);
    load_lds16(A + (size_t)ra1 * K + k0 + ac1, &sA[c1 * 8]);
    load_lds16(Bb + (size_t)ar0 * K + k0 + ac0, &sB[c0 * 8]);
    load_lds16(Bb + (size_t)ar1 * K + k0 + ac1, &sB[c1 * 8]);
    __syncthreads();
    bf16x8 af[4], bfr[4];
    int kq = (lane >> 4) * 8;
    int mr = wm + (lane & 15);
    int nr = wn + (lane & 15);
#pragma unroll
    for (int i = 0; i < 4; ++i) af[i] = *(const bf16x8*)&sA[(mr + i * 16) * 32 + kq];
#pragma unroll
    for (int j = 0; j < 4; ++j) bfr[j] = *(const bf16x8*)&sB[(nr + j * 16) * 32 + kq];
#pragma unroll
    for (int i = 0; i < 4; ++i)
#pragma unroll
      for (int j = 0; j < 4; ++j)
        acc[i][j] = __builtin_amdgcn_mfma_f32_16x16x32_bf16(af[i], bfr[j], acc[i][j], 0, 0, 0);
    __syncthreads();
  }
  int quad = lane >> 4;
  int lc = lane & 15;
#pragma unroll
  for (int i = 0; i < 4; ++i) {
#pragma unroll
    for (int r2 = 0; r2 < 4; ++r2) {
      int gm = mblk + wm + i * 16 + quad * 4 + r2;
      if (gm < M) {
#pragma unroll
        for (int j = 0; j < 4; ++j) {
          int gn = nblk + wn + j * 16 + lc;
          float v = acc[i][j][r2];
          if (BIAS_RELU) { v += bias[gn]; v = v >= 0.f ? v : 0.2f * v; }
          C[(size_t)gm * N + gn] = f2b(v);
        }
      }
    }
  }
}

extern "C" void kernel_launch(void* const* d_in, const int* in_sizes, int n_in,
                              void* d_out, int out_size, void* d_ws, size_t ws_size,
                              hipStream_t stream) {
  (void)in_sizes; (void)n_in; (void)out_size;
  const float* x  = (const float*)d_in[0];
  const int* erow = (const int*)d_in[1];
  const int* ecol = (const int*)d_in[2];
  const float* ev = (const float*)d_in[3];
  const float* W0 = (const float*)d_in[4];
  const float* b0 = (const float*)d_in[5];
  const float* W1 = (const float*)d_in[6];
  const float* b1 = (const float*)d_in[7];
  const float* W2 = (const float*)d_in[8];
  const float* b2 = (const float*)d_in[9];

  // ---- persistent meta (after the activation pool) ----
  const size_t POOL_T1 = 256000000;   // h1 full (204.8M, norm_out overlaid) + spmm0_out
  const size_t POOL_T2 = 204800000;   // norm + spmm0 + h1 half-chunk
  const size_t POOL_T3 = 153600000;   // norm + spmm0 + h1 quarter-chunk
  const size_t META = 12800000 + 200064 + 7340032;
  int tier = (ws_size >= POOL_T1 + META) ? 1 : (ws_size >= POOL_T2 + META) ? 2 : 3;
  size_t pool_sz = (tier == 1) ? POOL_T1 : (tier == 2) ? POOL_T2 : POOL_T3;

  char* ws = (char*)d_ws;
  int2*  ep   = (int2*)(ws + pool_sz);
  int*   rs_s = (int*)(ws + pool_sz + 12800000);
  unsigned short* w0t = (unsigned short*)(ws + pool_sz + 12800000 + 200064);
  unsigned short* w1t = w0t + (size_t)2048 * 512;
  unsigned short* w2t = w1t + (size_t)1024 * 2048;
  // build-time transients live in the (then-dead) activation pool
  int* rs2   = (int*)(ws);                  // (650000+1)*4
  int* csum  = (int*)(ws + 2600064);        // 4KB
  int* head2 = (int*)(ws + 2604160);        // 2.6MB
  unsigned short* u = (unsigned short*)d_out;  // [N,1024] bf16 scratch

  // ---- CSR build: edges ordered by (row, col>>12) for L2 sweep locality ----
  hipMemsetAsync(rs2, 0, 2600064, stream);
  hist2_k<<<6250, 256, 0, stream>>>(erow, ecol, rs2);
  scan1_k<<<635, 256, 0, stream>>>(rs2, rs2, csum, N_NODES * NCB);
  scan2p_k<<<1, 256, 0, stream>>>(csum, 635);
  scan3_k<<<2540, 256, 0, stream>>>(rs2, csum, N_NODES * NCB);
  extract_k<<<196, 256, 0, stream>>>(rs2, rs_s);
  hipMemcpyAsync(head2, rs2, (size_t)N_NODES * NCB * 4, hipMemcpyDeviceToDevice, stream);
  scatter2_k<<<6250, 256, 0, stream>>>(erow, ecol, ev, head2, ep);

  // ---- weights -> transposed bf16 (single launch) ----
  wconv3_k<<<14336, 256, 0, stream>>>(W0, W1, W2, w0t, w1t, w2t);

  if (tier == 1) {
    unsigned short* h1        = (unsigned short*)(ws);              // 204.8M
    unsigned short* norm_out  = (unsigned short*)(ws);              // overlays h1 (dead before h1 written)
    unsigned short* spmm0_out = (unsigned short*)(ws + 204800000);  // 51.2M
    unsigned short* h2        = (unsigned short*)(ws);              // overlays h1 (dead)
    unsigned short* vbuf      = (unsigned short*)(ws + 102400000);
    normalize_k<<<12500, 256, 0, stream>>>(x, norm_out);
    spmm_k<512, 0><<<12500, 256, 0, stream>>>(norm_out, rs_s, ep, nullptr, spmm0_out);
    gemm_bt_k<true ><<<16 * 391, 256, 0, stream>>>(spmm0_out, w0t, b0, h1, N_NODES, 2048, 512, 16);
    gemm_bt_k<false><<<8 * 391, 256, 0, stream>>>(h1, w1t, nullptr, u, N_NODES, 1024, 2048, 8);
    spmm_k<1024, 1><<<25000, 256, 0, stream>>>(u, rs_s, ep, b1, h2);
    gemm_bt_k<false><<<4 * 391, 256, 0, stream>>>(h2, w2t, nullptr, vbuf, N_NODES, 512, 1024, 4);
    spmm_k<512, 2><<<12500, 256, 0, stream>>>(vbuf, rs_s, ep, b2, (float*)d_out);
  } else {
    int nchunk = (tier == 2) ? 2 : 4;
    int crows = (tier == 2) ? 25000 : 12500;
    int ytiles = (tier == 2) ? 196 : 98;
    unsigned short* norm_out  = (unsigned short*)(ws);
    unsigned short* spmm0_out = (unsigned short*)(ws + 51200000);
    unsigned short* h1chunk   = (unsigned short*)(ws + 102400000);
    unsigned short* h2        = (unsigned short*)(ws);
    unsigned short* vbuf      = (unsigned short*)(ws + 102400000);
    normalize_k<<<12500, 256, 0, stream>>>(x, norm_out);
    spmm_k<512, 0><<<12500, 256, 0, stream>>>(norm_out, rs_s, ep, nullptr, spmm0_out);
    for (int c = 0; c < nchunk; ++c) {
      const unsigned short* a0 = spmm0_out + (size_t)c * crows * 512;
      unsigned short* uc = u + (size_t)c * crows * 1024;
      gemm_bt_k<true ><<<16 * ytiles, 256, 0, stream>>>(a0, w0t, b0, h1chunk, crows, 2048, 512, 16);
      gemm_bt_k<false><<<8 * ytiles, 256, 0, stream>>>(h1chunk, w1t, nullptr, uc, crows, 1024, 2048, 8);
    }
    spmm_k<1024, 1><<<25000, 256, 0, stream>>>(u, rs_s, ep, b1, h2);
    gemm_bt_k<false><<<4 * 391, 256, 0, stream>>>(h2, w2t, nullptr, vbuf, N_NODES, 512, 1024, 4);
    spmm_k<512, 2><<<12500, 256, 0, stream>>>(vbuf, rs_s, ep, b2, (float*)d_out);
  }
}